// Round 9
// baseline (170.074 us; speedup 1.0000x reference)
//
#include <hip/hip_runtime.h>
#include <math.h>

// out = softmax((Q .* K^T) / 64 .* V, axis=1)   (elementwise, NOT matmul)
// Q: [8192,4096] f32; K: [4096,8192] f32 (need K[j][i]); V,O: [8192,4096].
//
// R9: R4/R7/R8 all hit the same ~150us wall regardless of schedule (lockstep
// vs barrier-free, 8 vs 16 waves) at 2.3 TB/s, VALU 6%. Shared factor: the
// K gather = 32B segments at 32KiB power-of-2 stride (DRAM-activate-heavy).
// Fix: (1) tiled transpose K->KT into d_ws with 1KiB-contiguous reads and
// 256B-contiguous writes; (2) pure row-streaming softmax (no LDS/barriers,
// all row-major, 4-tile lookahead, payload in 16 NAMED float4 regs).
// Fallback to the R8 kernel if ws_size < 128 MiB.

static constexpr int NROW = 8192;        // rows of Q/V/O; cols of K
static constexpr int D    = 4096;        // cols of Q/V/O; rows of K
static constexpr float SCL = 0.015625f;  // 1/64 exact

// =================== Kernel 1: transpose K [D][NROW] -> KT [NROW][D] ======
// tile = 64 j x 256 i. Reads: 1KiB contiguous per K row. Writes: 256B
// contiguous per KT row. LDS pad 257 -> write-side reads are 2-way (free).
__global__ __launch_bounds__(256, 2)
void kt_transpose_kernel(const float* __restrict__ K, float* __restrict__ KT)
{
    __shared__ float lds[64][257];
    const int t  = threadIdx.x;
    const int jt = blockIdx.x & 63;       // 64 j-tiles (D/64)
    const int it = blockIdx.x >> 6;       // 32 i-tiles (NROW/256)
    const int j0 = jt * 64;
    const int i0 = it * 256;

    const int rr = t >> 6;                // wave id: fixed j-row offset
    const int i4 = t & 63;                // float4 column within tile
    #pragma unroll
    for (int s = 0; s < 16; ++s) {
        const int jr = s * 4 + rr;
        const float4 v =
            *(const float4*)(K + (size_t)(j0 + jr) * NROW + i0 + 4 * i4);
        *(float4*)&lds[jr][4 * i4] = v;   // contiguous b128, conflict-free
    }
    __syncthreads();

    const int j4 = t & 15;                // j quad within tile
    const int ir = t >> 4;                // 0..15
    #pragma unroll
    for (int sw = 0; sw < 16; ++sw) {
        const int il = sw * 16 + ir;      // 0..255
        float4 w;
        w.x = lds[4 * j4 + 0][il];
        w.y = lds[4 * j4 + 1][il];
        w.z = lds[4 * j4 + 2][il];
        w.w = lds[4 * j4 + 3][il];
        *(float4*)(KT + (size_t)(i0 + il) * D + j0 + 4 * j4) = w;
    }
}

// =================== Kernel 2: pure row-streaming softmax =================
// Block = 4 waves = 4 rows (256 thr). Wave owns a row; all loads row-major
// float4; 4-tile lookahead slots; payload 16 named float4; butterfly sum.
__global__ __launch_bounds__(256, 3)     // <=170 regs, 12 waves/CU
void sdp_stream_kernel(const float* __restrict__ Q,
                       const float* __restrict__ KT,
                       const float* __restrict__ V,
                       float* __restrict__ O)
{
    const int tid  = threadIdx.x;
    const int wv   = tid >> 6;
    const int lane = tid & 63;
    const int r    = blockIdx.x * 4 + wv;

    const float* qrow = Q  + (size_t)r * D;
    const float* krow = KT + (size_t)r * D;
    const float* vrow = V  + (size_t)r * D;
    float*       orow = O  + (size_t)r * D;
    const int c0 = 4 * lane;

    // 4 lookahead slots (tiles t, t+1, t+2, t+3)
    float4 qA = *(const float4*)(qrow + 0 * 256 + c0);
    float4 kA = *(const float4*)(krow + 0 * 256 + c0);
    float4 vA = *(const float4*)(vrow + 0 * 256 + c0);
    float4 qB = *(const float4*)(qrow + 1 * 256 + c0);
    float4 kB = *(const float4*)(krow + 1 * 256 + c0);
    float4 vB = *(const float4*)(vrow + 1 * 256 + c0);
    float4 qC = *(const float4*)(qrow + 2 * 256 + c0);
    float4 kC = *(const float4*)(krow + 2 * 256 + c0);
    float4 vC = *(const float4*)(vrow + 2 * 256 + c0);
    float4 qD = *(const float4*)(qrow + 3 * 256 + c0);
    float4 kD = *(const float4*)(krow + 3 * 256 + c0);
    float4 vD = *(const float4*)(vrow + 3 * 256 + c0);

    float4 e0, e1, e2, e3, e4, e5, e6, e7,
           e8, e9, e10, e11, e12, e13, e14, e15;
    float s = 0.0f;

    // Body t: consume slot, refill it with tile t+4 (stays in flight ~4
    // bodies), exp, accumulate. No barriers, no LDS.
#define BODY(t, ET, QS, KS, VS)                                               \
    {                                                                         \
        const float4 qc = QS, kc = KS, vc = VS;                               \
        if ((t) + 4 < 16) {                                                   \
            QS = *(const float4*)(qrow + ((t) + 4) * 256 + c0);               \
            KS = *(const float4*)(krow + ((t) + 4) * 256 + c0);               \
            VS = *(const float4*)(vrow + ((t) + 4) * 256 + c0);               \
        }                                                                     \
        ET.x = __expf(((qc.x * kc.x) * SCL) * vc.x);                          \
        ET.y = __expf(((qc.y * kc.y) * SCL) * vc.y);                          \
        ET.z = __expf(((qc.z * kc.z) * SCL) * vc.z);                          \
        ET.w = __expf(((qc.w * kc.w) * SCL) * vc.w);                          \
        s += ((ET.x + ET.y) + (ET.z + ET.w));                                 \
        __builtin_amdgcn_sched_barrier(0);                                    \
    }

    BODY(0,  e0,  qA, kA, vA)
    BODY(1,  e1,  qB, kB, vB)
    BODY(2,  e2,  qC, kC, vC)
    BODY(3,  e3,  qD, kD, vD)
    BODY(4,  e4,  qA, kA, vA)
    BODY(5,  e5,  qB, kB, vB)
    BODY(6,  e6,  qC, kC, vC)
    BODY(7,  e7,  qD, kD, vD)
    BODY(8,  e8,  qA, kA, vA)
    BODY(9,  e9,  qB, kB, vB)
    BODY(10, e10, qC, kC, vC)
    BODY(11, e11, qD, kD, vD)
    BODY(12, e12, qA, kA, vA)
    BODY(13, e13, qB, kB, vB)
    BODY(14, e14, qC, kC, vC)
    BODY(15, e15, qD, kD, vD)
#undef BODY

    // row sum: butterfly across the wave's 64 lanes
    #pragma unroll
    for (int i = 1; i < 64; i <<= 1)
        s += __shfl_xor(s, i, 64);
    const float inv = 1.0f / s;

#define WRITE_TILE(t, ET)                                                     \
    {                                                                         \
        float4 xx = ET;                                                       \
        xx.x *= inv; xx.y *= inv; xx.z *= inv; xx.w *= inv;                   \
        *(float4*)(orow + (size_t)(t) * 256 + c0) = xx;                       \
    }

    WRITE_TILE(0,  e0)  WRITE_TILE(1,  e1)  WRITE_TILE(2,  e2)  WRITE_TILE(3,  e3)
    WRITE_TILE(4,  e4)  WRITE_TILE(5,  e5)  WRITE_TILE(6,  e6)  WRITE_TILE(7,  e7)
    WRITE_TILE(8,  e8)  WRITE_TILE(9,  e9)  WRITE_TILE(10, e10) WRITE_TILE(11, e11)
    WRITE_TILE(12, e12) WRITE_TILE(13, e13) WRITE_TILE(14, e14) WRITE_TILE(15, e15)
#undef WRITE_TILE
}

// =================== Fallback (R8): used only if ws is too small ==========
static constexpr int RPB_F  = 8;
static constexpr int HALF_F = 2048;
static constexpr int LSTR_F = HALF_F + 4;

#define LDS_BARRIER() asm volatile("s_waitcnt lgkmcnt(0)\n\ts_barrier" ::: "memory")

__global__ __launch_bounds__(512, 4)
void sdp_softmax_fallback(const float* __restrict__ Q,
                          const float* __restrict__ K,
                          const float* __restrict__ V,
                          float* __restrict__ O)
{
    __shared__ float ldsK[RPB_F * LSTR_F];

    const int tid  = threadIdx.x;
    const int wv   = tid >> 6;
    const int lane = tid & 63;
    const int nwg = gridDim.x;
    const int cpx = nwg >> 3;
    const int hb  = blockIdx.x;
    const int lb  = (hb & 7) * cpx + (hb >> 3);
    const int row0 = lb * RPB_F;
    const int r    = row0 + wv;

    const float* qrow = Q + (size_t)r * D;
    const float* vrow = V + (size_t)r * D;
    float*       orow = O + (size_t)r * D;

    const int il = tid & 7;
    const int jg = tid >> 3;
    const float* kbase = K + (size_t)(8 * jg) * NROW + (size_t)row0 + il;

    float sa0, sa1, sa2, sa3, sa4, sa5, sa6, sa7;
    float sb0, sb1, sb2, sb3, sb4, sb5, sb6, sb7;
    float sc0, sc1, sc2, sc3, sc4, sc5, sc6, sc7;
    float sd0, sd1, sd2, sd3, sd4, sd5, sd6, sd7;

#define LOADB(R, J0)                                                          \
    {                                                                         \
        const float* p = kbase + (size_t)(J0) * NROW;                         \
        R##0 = p[0];                  R##1 = p[NROW];                         \
        R##2 = p[2 * (size_t)NROW];   R##3 = p[3 * (size_t)NROW];             \
        R##4 = p[4 * (size_t)NROW];   R##5 = p[5 * (size_t)NROW];             \
        R##6 = p[6 * (size_t)NROW];   R##7 = p[7 * (size_t)NROW];             \
    }
#define WRITEB(R, COL)                                                        \
    {                                                                         \
        float* w = &ldsK[il * LSTR_F + (COL) + 8 * jg];                       \
        *(float4*)w       = make_float4(R##0, R##1, R##2, R##3);              \
        *(float4*)(w + 4) = make_float4(R##4, R##5, R##6, R##7);              \
    }

    LOADB(sa, 0)
    float4 qP0 = *(const float4*)(qrow + 0 * 256 + 4 * lane);
    float4 vP0 = *(const float4*)(vrow + 0 * 256 + 4 * lane);
    float4 qP1 = *(const float4*)(qrow + 1 * 256 + 4 * lane);
    float4 vP1 = *(const float4*)(vrow + 1 * 256 + 4 * lane);
    float4 qP2 = *(const float4*)(qrow + 2 * 256 + 4 * lane);
    float4 vP2 = *(const float4*)(vrow + 2 * 256 + 4 * lane);
    float4 qP3 = *(const float4*)(qrow + 3 * 256 + 4 * lane);
    float4 vP3 = *(const float4*)(vrow + 3 * 256 + 4 * lane);

    LOADB(sb, 512)   WRITEB(sa, 0)
    LOADB(sa, 1024)  WRITEB(sb, 512)
    LOADB(sb, 1536)  WRITEB(sa, 1024)
    WRITEB(sb, 1536)

    LDS_BARRIER();

    float4 e0, e1, e2, e3, e4, e5, e6, e7,
           e8, e9, e10, e11, e12, e13, e14, e15;
    float s = 0.0f;

#define BODY(t, ET, QS, VS)                                                   \
    {                                                                         \
        const float4 qc = QS, vc = VS;                                        \
        if ((t) + 4 < 16) {                                                   \
            QS = *(const float4*)(qrow + ((t) + 4) * 256 + 4 * lane);         \
            VS = *(const float4*)(vrow + ((t) + 4) * 256 + 4 * lane);         \
        }                                                                     \
        const float4 kf =                                                     \
            *(const float4*)&ldsK[wv * LSTR_F + ((t) & 7) * 256 + 4 * lane];  \
        ET.x = __expf(((qc.x * kf.x) * SCL) * vc.x);                          \
        ET.y = __expf(((qc.y * kf.y) * SCL) * vc.y);                          \
        ET.z = __expf(((qc.z * kf.z) * SCL) * vc.z);                          \
        ET.w = __expf(((qc.w * kf.w) * SCL) * vc.w);                          \
        s += ((ET.x + ET.y) + (ET.z + ET.w));                                 \
        __builtin_amdgcn_sched_barrier(0);                                    \
    }

    BODY(0,  e0,  qP0, vP0)
    BODY(1,  e1,  qP1, vP1)
    BODY(2,  e2,  qP2, vP2)
    LOADB(sa, 2048)
    BODY(3,  e3,  qP3, vP3)
    BODY(4,  e4,  qP0, vP0)
    LOADB(sb, 2560)
    BODY(5,  e5,  qP1, vP1)
    BODY(6,  e6,  qP2, vP2)
    LOADB(sc, 3072)
    BODY(7,  e7,  qP3, vP3)
    LOADB(sd, 3584)

    LDS_BARRIER();
    WRITEB(sa, 0)
    WRITEB(sb, 512)
    WRITEB(sc, 1024)
    WRITEB(sd, 1536)
    LDS_BARRIER();

    BODY(8,  e8,  qP0, vP0)
    BODY(9,  e9,  qP1, vP1)
    BODY(10, e10, qP2, vP2)
    BODY(11, e11, qP3, vP3)
    BODY(12, e12, qP0, vP0)
    BODY(13, e13, qP1, vP1)
    BODY(14, e14, qP2, vP2)
    BODY(15, e15, qP3, vP3)
#undef BODY
#undef LOADB
#undef WRITEB

    #pragma unroll
    for (int i = 1; i < 64; i <<= 1)
        s += __shfl_xor(s, i, 64);
    const float inv = 1.0f / s;

#define WRITE_TILE(t, ET)                                                     \
    {                                                                         \
        float4 xx = ET;                                                       \
        xx.x *= inv; xx.y *= inv; xx.z *= inv; xx.w *= inv;                   \
        *(float4*)(orow + (size_t)(t) * 256 + 4 * lane) = xx;                 \
    }

    WRITE_TILE(0,  e0)  WRITE_TILE(1,  e1)  WRITE_TILE(2,  e2)  WRITE_TILE(3,  e3)
    WRITE_TILE(4,  e4)  WRITE_TILE(5,  e5)  WRITE_TILE(6,  e6)  WRITE_TILE(7,  e7)
    WRITE_TILE(8,  e8)  WRITE_TILE(9,  e9)  WRITE_TILE(10, e10) WRITE_TILE(11, e11)
    WRITE_TILE(12, e12) WRITE_TILE(13, e13) WRITE_TILE(14, e14) WRITE_TILE(15, e15)
#undef WRITE_TILE
}

extern "C" void kernel_launch(void* const* d_in, const int* in_sizes, int n_in,
                              void* d_out, int out_size, void* d_ws, size_t ws_size,
                              hipStream_t stream) {
    const float* Q = (const float*)d_in[0];
    const float* K = (const float*)d_in[1];
    const float* V = (const float*)d_in[2];
    float* O = (float*)d_out;

    const size_t kt_bytes = (size_t)NROW * D * sizeof(float);   // 128 MiB
    if (ws_size >= kt_bytes) {
        float* KT = (float*)d_ws;
        kt_transpose_kernel<<<dim3(64 * 32), dim3(256), 0, stream>>>(K, KT);
        sdp_stream_kernel<<<dim3(NROW / 4), dim3(256), 0, stream>>>(Q, KT, V, O);
    } else {
        sdp_softmax_fallback<<<dim3(NROW / RPB_F), dim3(512), 0, stream>>>(Q, K, V, O);
    }
}

// Round 10
// 140.347 us; speedup vs baseline: 1.2118x; 1.2118x over previous
//
#include <hip/hip_runtime.h>
#include <math.h>

// out = softmax((Q .* K^T) / 64 .* V, axis=1)   (elementwise, NOT matmul)
// Q: [8192,4096] f32; K: [4096,8192] f32 (need K[j][i]); V,O: [8192,4096].
//
// R10: two-pass, both passes contiguous.
//  Pass 1: tiled transpose K -> KT in BF16 (ws): halves KT traffic; KT
//          (64 MiB) then L3-resident for pass 2.
//  Pass 2: row-streaming softmax; e-payload packed to bf16 (16 x ushort4 =
//          32 regs vs 64) -> total regs ~100 -> 5 waves/SIMD (R9's hidden
//          AGPR payload capped all prior rounds at 3 waves/SIMD, Occ 27%).
// Precision: |x| <= ~0.06 -> bf16-K delta-p ~1e-7; bf16-e delta-p ~5e-7
// (sum taken from f32 e before packing). Threshold 8.39e-6, current 1.9e-6.

static constexpr int NROW = 8192;
static constexpr int D    = 4096;
static constexpr float SCL = 0.015625f;  // 1/64 exact

__device__ __forceinline__ unsigned short f2bf(float f) {
    unsigned int b = __float_as_uint(f);
    b = (b + 0x7FFFu + ((b >> 16) & 1u)) >> 16;      // round-nearest-even
    return (unsigned short)b;
}
__device__ __forceinline__ float bf2f(unsigned short u) {
    return __uint_as_float(((unsigned int)u) << 16);
}

// ============ Kernel 1: transpose K [D][NROW] -> KT bf16 [NROW][D] ========
// tile = 64 j x 256 i. Reads 1KiB contiguous per K row; writes 128B
// contiguous bf16 segments per KT row. LDS f32 64x257 (write-side reads are
// 2-way = free; verified R9). Convert f32->bf16 at the write.
__global__ __launch_bounds__(256, 2)
void kt_transpose_kernel(const float* __restrict__ K,
                         unsigned short* __restrict__ KT)
{
    __shared__ float lds[64][257];
    const int t  = threadIdx.x;
    const int jt = blockIdx.x & 63;       // 64 j-tiles (D/64)
    const int it = blockIdx.x >> 6;       // 32 i-tiles (NROW/256)
    const int j0 = jt * 64;
    const int i0 = it * 256;

    const int rr = t >> 6;                // wave id -> j row offset
    const int i4 = t & 63;                // float4 column within tile
    #pragma unroll
    for (int s = 0; s < 16; ++s) {
        const int jr = s * 4 + rr;
        const float4 v =
            *(const float4*)(K + (size_t)(j0 + jr) * NROW + i0 + 4 * i4);
        *(float4*)&lds[jr][4 * i4] = v;
    }
    __syncthreads();

    const int j4 = t & 15;                // j quad within tile
    const int ir = t >> 4;                // 0..15
    #pragma unroll
    for (int sw = 0; sw < 16; ++sw) {
        const int il = sw * 16 + ir;      // 0..255
        ushort4 w;
        w.x = f2bf(lds[4 * j4 + 0][il]);
        w.y = f2bf(lds[4 * j4 + 1][il]);
        w.z = f2bf(lds[4 * j4 + 2][il]);
        w.w = f2bf(lds[4 * j4 + 3][il]);
        *(ushort4*)(KT + (size_t)(i0 + il) * D + j0 + 4 * j4) = w;
    }
}

// ============ Kernel 2: row-streaming softmax (bf16 KT, bf16 payload) =====
// Block = 4 waves = 4 rows. Wave owns a row. 4-tile lookahead slots.
// Payload: 16 named ushort4 (packed bf16 e). No LDS, no barriers.
__global__ __launch_bounds__(256, 4)
void sdp_stream_kernel(const float* __restrict__ Q,
                       const unsigned short* __restrict__ KT,
                       const float* __restrict__ V,
                       float* __restrict__ O)
{
    const int tid  = threadIdx.x;
    const int wv   = tid >> 6;
    const int lane = tid & 63;
    const int r    = blockIdx.x * 4 + wv;

    const float*          qrow = Q  + (size_t)r * D;
    const unsigned short* krow = KT + (size_t)r * D;
    const float*          vrow = V  + (size_t)r * D;
    float*                orow = O  + (size_t)r * D;
    const int c0 = 4 * lane;

    // 4 lookahead slots (tiles t..t+3)
    float4  qA = *(const float4*)(qrow + 0 * 256 + c0);
    ushort4 kA = *(const ushort4*)(krow + 0 * 256 + c0);
    float4  vA = *(const float4*)(vrow + 0 * 256 + c0);
    float4  qB = *(const float4*)(qrow + 1 * 256 + c0);
    ushort4 kB = *(const ushort4*)(krow + 1 * 256 + c0);
    float4  vB = *(const float4*)(vrow + 1 * 256 + c0);
    float4  qC = *(const float4*)(qrow + 2 * 256 + c0);
    ushort4 kC = *(const ushort4*)(krow + 2 * 256 + c0);
    float4  vC = *(const float4*)(vrow + 2 * 256 + c0);
    float4  qD = *(const float4*)(qrow + 3 * 256 + c0);
    ushort4 kD = *(const ushort4*)(krow + 3 * 256 + c0);
    float4  vD = *(const float4*)(vrow + 3 * 256 + c0);

    ushort4 e0, e1, e2, e3, e4, e5, e6, e7,
            e8, e9, e10, e11, e12, e13, e14, e15;
    float s = 0.0f;

    // Body t: consume slot, refill with tile t+4 (in flight ~4 bodies),
    // exp in f32 (sum from f32), pack to bf16 payload.
#define BODY(t, ET, QS, KS, VS)                                               \
    {                                                                         \
        const float4 qc = QS; const ushort4 kc = KS; const float4 vc = VS;    \
        if ((t) + 4 < 16) {                                                   \
            QS = *(const float4*)(qrow + ((t) + 4) * 256 + c0);               \
            KS = *(const ushort4*)(krow + ((t) + 4) * 256 + c0);              \
            VS = *(const float4*)(vrow + ((t) + 4) * 256 + c0);               \
        }                                                                     \
        const float ex = __expf(((qc.x * bf2f(kc.x)) * SCL) * vc.x);          \
        const float ey = __expf(((qc.y * bf2f(kc.y)) * SCL) * vc.y);          \
        const float ez = __expf(((qc.z * bf2f(kc.z)) * SCL) * vc.z);          \
        const float ew = __expf(((qc.w * bf2f(kc.w)) * SCL) * vc.w);          \
        s += ((ex + ey) + (ez + ew));                                         \
        ET.x = f2bf(ex); ET.y = f2bf(ey); ET.z = f2bf(ez); ET.w = f2bf(ew);   \
        __builtin_amdgcn_sched_barrier(0);                                    \
    }

    BODY(0,  e0,  qA, kA, vA)
    BODY(1,  e1,  qB, kB, vB)
    BODY(2,  e2,  qC, kC, vC)
    BODY(3,  e3,  qD, kD, vD)
    BODY(4,  e4,  qA, kA, vA)
    BODY(5,  e5,  qB, kB, vB)
    BODY(6,  e6,  qC, kC, vC)
    BODY(7,  e7,  qD, kD, vD)
    BODY(8,  e8,  qA, kA, vA)
    BODY(9,  e9,  qB, kB, vB)
    BODY(10, e10, qC, kC, vC)
    BODY(11, e11, qD, kD, vD)
    BODY(12, e12, qA, kA, vA)
    BODY(13, e13, qB, kB, vB)
    BODY(14, e14, qC, kC, vC)
    BODY(15, e15, qD, kD, vD)
#undef BODY

    // row sum: butterfly across the wave's 64 lanes
    #pragma unroll
    for (int i = 1; i < 64; i <<= 1)
        s += __shfl_xor(s, i, 64);
    const float inv = 1.0f / s;

#define WRITE_TILE(t, ET)                                                     \
    {                                                                         \
        float4 xx;                                                            \
        xx.x = bf2f(ET.x) * inv;                                              \
        xx.y = bf2f(ET.y) * inv;                                              \
        xx.z = bf2f(ET.z) * inv;                                              \
        xx.w = bf2f(ET.w) * inv;                                              \
        *(float4*)(orow + (size_t)(t) * 256 + c0) = xx;                       \
    }

    WRITE_TILE(0,  e0)  WRITE_TILE(1,  e1)  WRITE_TILE(2,  e2)  WRITE_TILE(3,  e3)
    WRITE_TILE(4,  e4)  WRITE_TILE(5,  e5)  WRITE_TILE(6,  e6)  WRITE_TILE(7,  e7)
    WRITE_TILE(8,  e8)  WRITE_TILE(9,  e9)  WRITE_TILE(10, e10) WRITE_TILE(11, e11)
    WRITE_TILE(12, e12) WRITE_TILE(13, e13) WRITE_TILE(14, e14) WRITE_TILE(15, e15)
#undef WRITE_TILE
}

extern "C" void kernel_launch(void* const* d_in, const int* in_sizes, int n_in,
                              void* d_out, int out_size, void* d_ws, size_t ws_size,
                              hipStream_t stream) {
    const float* Q = (const float*)d_in[0];
    const float* K = (const float*)d_in[1];
    const float* V = (const float*)d_in[2];
    float* O = (float*)d_out;

    unsigned short* KT = (unsigned short*)d_ws;      // 64 MiB (ws >=128 MiB, R9)
    kt_transpose_kernel<<<dim3(64 * 32), dim3(256), 0, stream>>>(K, KT);
    sdp_stream_kernel<<<dim3(NROW / 4), dim3(256), 0, stream>>>(Q, KT, V, O);
}

// Round 11
// 133.113 us; speedup vs baseline: 1.2777x; 1.0543x over previous
//
#include <hip/hip_runtime.h>
#include <math.h>

// out = softmax((Q .* K^T) / 64 .* V, axis=1)   (elementwise, NOT matmul)
// Q: [8192,4096] f32; K: [4096,8192] f32 (need K[j][i]); V,O: [8192,4096].
//
// R11: two-pass (transpose K->KT bf16 in ws, then contiguous row-stream),
// both passes occupancy-tuned:
//  Pass 1: tile 64j x 128i, LDS 64x129 f32 = 33 KB -> 4 blocks/CU (R10's
//          64x257 = 66 KB allowed only 2). Same access shapes.
//  Pass 2: 2 waves per row (32 e/lane = 16 bf16 payload regs vs 32) ->
//          ~75 total regs -> 6 waves/SIMD; cross-wave sum via 4-float LDS
//          + one barrier. 4-slot lookahead kept.
// Precision: bf16 K + bf16 e, sums in f32 -> absmax ~1.9e-6 (threshold 8.4e-6).

static constexpr int NROW = 8192;
static constexpr int D    = 4096;
static constexpr float SCL = 0.015625f;  // 1/64 exact

__device__ __forceinline__ unsigned short f2bf(float f) {
    unsigned int b = __float_as_uint(f);
    b = (b + 0x7FFFu + ((b >> 16) & 1u)) >> 16;      // round-nearest-even
    return (unsigned short)b;
}
__device__ __forceinline__ float bf2f(unsigned short u) {
    return __uint_as_float(((unsigned int)u) << 16);
}

// ============ Kernel 1: transpose K [D][NROW] -> KT bf16 [NROW][D] ========
// tile = 64 j x 128 i. Reads 512B contiguous per K row; writes 128B
// contiguous per KT row. LDS f32 [64][129]: transpose-read banks ~2-way.
__global__ __launch_bounds__(256, 4)
void kt_transpose_kernel(const float* __restrict__ K,
                         unsigned short* __restrict__ KT)
{
    __shared__ float lds[64][129];
    const int t  = threadIdx.x;
    const int jt = blockIdx.x & 63;       // 64 j-tiles (D/64)
    const int it = blockIdx.x >> 6;       // 64 i-tiles (NROW/128)
    const int j0 = jt * 64;
    const int i0 = it * 128;

    const int i4 = t & 31;                // float4 slot within 128-i row
    const int jb = t >> 5;                // 0..7
    #pragma unroll
    for (int s = 0; s < 8; ++s) {
        const int jr = s * 8 + jb;
        const float4 v =
            *(const float4*)(K + (size_t)(j0 + jr) * NROW + i0 + 4 * i4);
        *(float4*)&lds[jr][4 * i4] = v;
    }
    __syncthreads();

    const int j4 = t & 15;                // j quad within tile
    const int ib = t >> 4;                // 0..15
    #pragma unroll
    for (int sw = 0; sw < 8; ++sw) {
        const int il = sw * 16 + ib;      // 0..127
        ushort4 w;
        w.x = f2bf(lds[4 * j4 + 0][il]);
        w.y = f2bf(lds[4 * j4 + 1][il]);
        w.z = f2bf(lds[4 * j4 + 2][il]);
        w.w = f2bf(lds[4 * j4 + 3][il]);
        *(ushort4*)(KT + (size_t)(i0 + il) * D + j0 + 4 * j4) = w;
    }
}

// ============ Kernel 2: row-streaming softmax, 2 waves per row ============
// Block = 256 thr = 4 waves = 2 rows. Wave (wv) owns half a row:
// cols [ (wv&1)*2048, +2048 ). 8 tiles of 256 cols; 32 e/lane packed bf16
// (8 named ushort4 = 16 regs). 4-slot lookahead. One barrier (sum exchange).
__global__ __launch_bounds__(256, 6)
void sdp_stream_kernel(const float* __restrict__ Q,
                       const unsigned short* __restrict__ KT,
                       const float* __restrict__ V,
                       float* __restrict__ O)
{
    __shared__ float ssum[4];

    const int tid  = threadIdx.x;
    const int wv   = tid >> 6;            // 0..3
    const int lane = tid & 63;
    const int r    = blockIdx.x * 2 + (wv >> 1);
    const int hbase = (wv & 1) * 2048;    // column base of this wave's half

    const float*          qrow = Q  + (size_t)r * D + hbase;
    const unsigned short* krow = KT + (size_t)r * D + hbase;
    const float*          vrow = V  + (size_t)r * D + hbase;
    float*                orow = O  + (size_t)r * D + hbase;
    const int c0 = 4 * lane;

    // 4 lookahead slots (tiles t..t+3 of this half-row)
    float4  qA = *(const float4*)(qrow + 0 * 256 + c0);
    ushort4 kA = *(const ushort4*)(krow + 0 * 256 + c0);
    float4  vA = *(const float4*)(vrow + 0 * 256 + c0);
    float4  qB = *(const float4*)(qrow + 1 * 256 + c0);
    ushort4 kB = *(const ushort4*)(krow + 1 * 256 + c0);
    float4  vB = *(const float4*)(vrow + 1 * 256 + c0);
    float4  qC = *(const float4*)(qrow + 2 * 256 + c0);
    ushort4 kC = *(const ushort4*)(krow + 2 * 256 + c0);
    float4  vC = *(const float4*)(vrow + 2 * 256 + c0);
    float4  qD = *(const float4*)(qrow + 3 * 256 + c0);
    ushort4 kD = *(const ushort4*)(krow + 3 * 256 + c0);
    float4  vD = *(const float4*)(vrow + 3 * 256 + c0);

    ushort4 e0, e1, e2, e3, e4, e5, e6, e7;
    float s = 0.0f;

#define BODY(t, ET, QS, KS, VS)                                               \
    {                                                                         \
        const float4 qc = QS; const ushort4 kc = KS; const float4 vc = VS;    \
        if ((t) + 4 < 8) {                                                    \
            QS = *(const float4*)(qrow + ((t) + 4) * 256 + c0);               \
            KS = *(const ushort4*)(krow + ((t) + 4) * 256 + c0);              \
            VS = *(const float4*)(vrow + ((t) + 4) * 256 + c0);               \
        }                                                                     \
        const float ex = __expf(((qc.x * bf2f(kc.x)) * SCL) * vc.x);          \
        const float ey = __expf(((qc.y * bf2f(kc.y)) * SCL) * vc.y);          \
        const float ez = __expf(((qc.z * bf2f(kc.z)) * SCL) * vc.z);          \
        const float ew = __expf(((qc.w * bf2f(kc.w)) * SCL) * vc.w);          \
        s += ((ex + ey) + (ez + ew));                                         \
        ET.x = f2bf(ex); ET.y = f2bf(ey); ET.z = f2bf(ez); ET.w = f2bf(ew);   \
        __builtin_amdgcn_sched_barrier(0);                                    \
    }

    BODY(0, e0, qA, kA, vA)
    BODY(1, e1, qB, kB, vB)
    BODY(2, e2, qC, kC, vC)
    BODY(3, e3, qD, kD, vD)
    BODY(4, e4, qA, kA, vA)
    BODY(5, e5, qB, kB, vB)
    BODY(6, e6, qC, kC, vC)
    BODY(7, e7, qD, kD, vD)
#undef BODY

    // wave-local sum, then combine the two half-row waves through LDS
    #pragma unroll
    for (int i = 1; i < 64; i <<= 1)
        s += __shfl_xor(s, i, 64);
    if (lane == 0) ssum[wv] = s;
    __syncthreads();                       // all loads already consumed here
    const float inv = 1.0f / (ssum[wv] + ssum[wv ^ 1]);

#define WRITE_TILE(t, ET)                                                     \
    {                                                                         \
        float4 xx;                                                            \
        xx.x = bf2f(ET.x) * inv;                                              \
        xx.y = bf2f(ET.y) * inv;                                              \
        xx.z = bf2f(ET.z) * inv;                                              \
        xx.w = bf2f(ET.w) * inv;                                              \
        *(float4*)(orow + (size_t)(t) * 256 + c0) = xx;                       \
    }

    WRITE_TILE(0, e0)  WRITE_TILE(1, e1)  WRITE_TILE(2, e2)  WRITE_TILE(3, e3)
    WRITE_TILE(4, e4)  WRITE_TILE(5, e5)  WRITE_TILE(6, e6)  WRITE_TILE(7, e7)
#undef WRITE_TILE
}

extern "C" void kernel_launch(void* const* d_in, const int* in_sizes, int n_in,
                              void* d_out, int out_size, void* d_ws, size_t ws_size,
                              hipStream_t stream) {
    const float* Q = (const float*)d_in[0];
    const float* K = (const float*)d_in[1];
    const float* V = (const float*)d_in[2];
    float* O = (float*)d_out;

    unsigned short* KT = (unsigned short*)d_ws;      // 64 MiB
    kt_transpose_kernel<<<dim3(64 * 64), dim3(256), 0, stream>>>(K, KT);
    sdp_stream_kernel<<<dim3(NROW / 2), dim3(256), 0, stream>>>(Q, KT, V, O);
}

// Round 12
// 128.736 us; speedup vs baseline: 1.3211x; 1.0340x over previous
//
#include <hip/hip_runtime.h>
#include <math.h>

// out = softmax((Q .* K^T) / 64 .* V, axis=1)   (elementwise, NOT matmul)
// Q: [8192,4096] f32; K: [4096,8192] f32 (need K[j][i]); V,O: [8192,4096].
//
// R12: two-pass. Pass 1: tiled transpose K -> KT bf16 (R11, ~5 TB/s).
// Pass 2: row-stream with FULL upfront prefetch: block = 4 waves = 1 row,
// wave owns 1024 cols = 4 tiles; all 12 loads issued at wave start (lookahead
// = whole wave's work -> ONE latency exposure per wave, vs R11's per-body
// 280-cycle lead against ~900-cycle loaded latency). ~63 regs -> 7-8
// waves/SIMD. Cross-wave sum: 4-float LDS + one barrier (loads already
// consumed there, vmcnt drain harmless). Payload packed bf16 (sum from f32).

static constexpr int NROW = 8192;
static constexpr int D    = 4096;
static constexpr float SCL = 0.015625f;  // 1/64 exact

__device__ __forceinline__ unsigned short f2bf(float f) {
    unsigned int b = __float_as_uint(f);
    b = (b + 0x7FFFu + ((b >> 16) & 1u)) >> 16;      // round-nearest-even
    return (unsigned short)b;
}
__device__ __forceinline__ float bf2f(unsigned short u) {
    return __uint_as_float(((unsigned int)u) << 16);
}

// ============ Kernel 1: transpose K [D][NROW] -> KT bf16 [NROW][D] ========
// tile = 64 j x 128 i. Reads 512B contiguous per K row; writes 128B
// contiguous per KT row. LDS f32 [64][129]. (R11; ~5 TB/s, ~40 us)
__global__ __launch_bounds__(256, 4)
void kt_transpose_kernel(const float* __restrict__ K,
                         unsigned short* __restrict__ KT)
{
    __shared__ float lds[64][129];
    const int t  = threadIdx.x;
    const int jt = blockIdx.x & 63;       // 64 j-tiles (D/64)
    const int it = blockIdx.x >> 6;       // 64 i-tiles (NROW/128)
    const int j0 = jt * 64;
    const int i0 = it * 128;

    const int i4 = t & 31;                // float4 slot within 128-i row
    const int jb = t >> 5;                // 0..7
    #pragma unroll
    for (int s = 0; s < 8; ++s) {
        const int jr = s * 8 + jb;
        const float4 v =
            *(const float4*)(K + (size_t)(j0 + jr) * NROW + i0 + 4 * i4);
        *(float4*)&lds[jr][4 * i4] = v;
    }
    __syncthreads();

    const int j4 = t & 15;                // j quad within tile
    const int ib = t >> 4;                // 0..15
    #pragma unroll
    for (int sw = 0; sw < 8; ++sw) {
        const int il = sw * 16 + ib;      // 0..127
        ushort4 w;
        w.x = f2bf(lds[4 * j4 + 0][il]);
        w.y = f2bf(lds[4 * j4 + 1][il]);
        w.z = f2bf(lds[4 * j4 + 2][il]);
        w.w = f2bf(lds[4 * j4 + 3][il]);
        *(ushort4*)(KT + (size_t)(i0 + il) * D + j0 + 4 * j4) = w;
    }
}

// ============ Kernel 2: row-stream, full upfront prefetch =================
// Block = 256 thr = 4 waves = 1 row. Wave wv owns cols [wv*1024, +1024) =
// 4 tiles of 256. All 12 loads issued first; bodies consume in issue order
// (counted vmcnt). Payload: 4 named ushort4 (bf16). One barrier for the
// 4-way row sum.
__global__ __launch_bounds__(256, 6)
void sdp_stream_kernel(const float* __restrict__ Q,
                       const unsigned short* __restrict__ KT,
                       const float* __restrict__ V,
                       float* __restrict__ O)
{
    __shared__ float ssum[4];

    const int tid  = threadIdx.x;
    const int wv   = tid >> 6;            // 0..3
    const int lane = tid & 63;
    const int r    = blockIdx.x;          // one row per block
    const int base = wv * 1024;           // wave's column base

    const float*          qrow = Q  + (size_t)r * D + base;
    const unsigned short* krow = KT + (size_t)r * D + base;
    const float*          vrow = V  + (size_t)r * D + base;
    float*                orow = O  + (size_t)r * D + base;
    const int c0 = 4 * lane;

    // ---- all 12 loads up front (oldest = tile 0, consumed first) ----
    float4  q0 = *(const float4*)(qrow + 0 * 256 + c0);
    ushort4 k0 = *(const ushort4*)(krow + 0 * 256 + c0);
    float4  v0 = *(const float4*)(vrow + 0 * 256 + c0);
    float4  q1 = *(const float4*)(qrow + 1 * 256 + c0);
    ushort4 k1 = *(const ushort4*)(krow + 1 * 256 + c0);
    float4  v1 = *(const float4*)(vrow + 1 * 256 + c0);
    float4  q2 = *(const float4*)(qrow + 2 * 256 + c0);
    ushort4 k2 = *(const ushort4*)(krow + 2 * 256 + c0);
    float4  v2 = *(const float4*)(vrow + 2 * 256 + c0);
    float4  q3 = *(const float4*)(qrow + 3 * 256 + c0);
    ushort4 k3 = *(const ushort4*)(krow + 3 * 256 + c0);
    float4  v3 = *(const float4*)(vrow + 3 * 256 + c0);

    ushort4 e0, e1, e2, e3;
    float s = 0.0f;

#define BODY(ET, QS, KS, VS)                                                  \
    {                                                                         \
        const float ex = __expf(((QS.x * bf2f(KS.x)) * SCL) * VS.x);          \
        const float ey = __expf(((QS.y * bf2f(KS.y)) * SCL) * VS.y);          \
        const float ez = __expf(((QS.z * bf2f(KS.z)) * SCL) * VS.z);          \
        const float ew = __expf(((QS.w * bf2f(KS.w)) * SCL) * VS.w);          \
        s += ((ex + ey) + (ez + ew));                                         \
        ET.x = f2bf(ex); ET.y = f2bf(ey); ET.z = f2bf(ez); ET.w = f2bf(ew);   \
    }

    BODY(e0, q0, k0, v0)
    BODY(e1, q1, k1, v1)
    BODY(e2, q2, k2, v2)
    BODY(e3, q3, k3, v3)
#undef BODY

    // wave-local sum, then 4-way combine through LDS (one barrier; no loads
    // outstanding here so the implicit vmcnt drain is free)
    #pragma unroll
    for (int i = 1; i < 64; i <<= 1)
        s += __shfl_xor(s, i, 64);
    if (lane == 0) ssum[wv] = s;
    __syncthreads();
    const float inv = 1.0f / (((ssum[0] + ssum[1]) + (ssum[2] + ssum[3])));

#define WRITE_TILE(t, ET)                                                     \
    {                                                                         \
        float4 xx;                                                            \
        xx.x = bf2f(ET.x) * inv;                                              \
        xx.y = bf2f(ET.y) * inv;                                              \
        xx.z = bf2f(ET.z) * inv;                                              \
        xx.w = bf2f(ET.w) * inv;                                              \
        *(float4*)(orow + (size_t)(t) * 256 + c0) = xx;                       \
    }

    WRITE_TILE(0, e0)  WRITE_TILE(1, e1)  WRITE_TILE(2, e2)  WRITE_TILE(3, e3)
#undef WRITE_TILE
}

extern "C" void kernel_launch(void* const* d_in, const int* in_sizes, int n_in,
                              void* d_out, int out_size, void* d_ws, size_t ws_size,
                              hipStream_t stream) {
    const float* Q = (const float*)d_in[0];
    const float* K = (const float*)d_in[1];
    const float* V = (const float*)d_in[2];
    float* O = (float*)d_out;

    unsigned short* KT = (unsigned short*)d_ws;      // 64 MiB
    kt_transpose_kernel<<<dim3(64 * 64), dim3(256), 0, stream>>>(K, KT);
    sdp_stream_kernel<<<dim3(NROW), dim3(256), 0, stream>>>(Q, KT, V, O);
}